// Round 1
// baseline (411.535 us; speedup 1.0000x reference)
//
#include <hip/hip_runtime.h>
#include <hip/hip_bf16.h>
#include <stdint.h>

typedef float f32x4 __attribute__((ext_vector_type(4)));
typedef __bf16 bf16x8 __attribute__((ext_vector_type(8)));

#define EPS 1e-5f

// ---- helpers ----
static __device__ __forceinline__ unsigned short f2bf(float f) {
  unsigned int u = __float_as_uint(f);
  unsigned int r = (u + 0x7fffu + ((u >> 16) & 1u)) >> 16;
  return (unsigned short)r;
}

static __device__ __forceinline__ void gload_lds16(const unsigned short* g, unsigned short* s) {
  __builtin_amdgcn_global_load_lds((const __attribute__((address_space(1))) unsigned int*)g,
                                   (__attribute__((address_space(3))) unsigned int*)s,
                                   16, 0, 0);
}

// ---- fp32 -> bf16 convert (vectorized) ----
__global__ void k_convert(const float* __restrict__ src, unsigned short* __restrict__ dst, int n4) {
  int idx = blockIdx.x * blockDim.x + threadIdx.x;
  int stride = gridDim.x * blockDim.x;
  for (int i = idx; i < n4; i += stride) {
    f32x4 v = ((const f32x4*)src)[i];
    ushort4 o;
    o.x = f2bf(v.x); o.y = f2bf(v.y); o.z = f2bf(v.z); o.w = f2bf(v.w);
    ((ushort4*)dst)[i] = o;
  }
}

// ---- alpha = sigmoid(A @ W_alpha^T + b) ; one block per token ----
__global__ __launch_bounds__(256) void k_alpha(const float* __restrict__ A,
                                               const float* __restrict__ Wa,
                                               const float* __restrict__ ba,
                                               float* __restrict__ alpha) {
  __shared__ __align__(16) float arow[1024];
  const int bt = blockIdx.x, tid = threadIdx.x;
  ((f32x4*)arow)[tid] = ((const f32x4*)(A + (size_t)bt * 1024))[tid];
  __syncthreads();
  const int c = tid >> 3, h = tid & 7;
  const float* wr = Wa + (size_t)c * 1024 + h * 128;
  const float* ar = arow + h * 128;
  float s = 0.f;
#pragma unroll 8
  for (int j = 0; j < 128; j += 4) {
    f32x4 wv = *(const f32x4*)(wr + j);
    s += wv.x * ar[j] + wv.y * ar[j + 1] + wv.z * ar[j + 2] + wv.w * ar[j + 3];
  }
  s += __shfl_down(s, 4);
  s += __shfl_down(s, 2);
  s += __shfl_down(s, 1);
  if (h == 0) {
    float z = s + ba[c];
    alpha[(size_t)bt * 32 + c] = 1.f / (1.f + __expf(-z));
  }
}

// ---- main GEMM: C[4096,16896] = A[4096,1024] @ W^T, bf16 in, bf16 out ----
// m97 structure: 128x128 tile, BK=32, 4 waves of 64x64, 16x16x32 MFMA.
__global__ __launch_bounds__(256) void k_gemm(const unsigned short* __restrict__ A,
                                              const unsigned short* __restrict__ W,
                                              unsigned short* __restrict__ C) {
  __shared__ __align__(16) unsigned short As[4096];  // [128][32]
  __shared__ __align__(16) unsigned short Bs[4096];  // [128][32]
  const int bid = blockIdx.x;
  const int tm = bid / 132, tn = bid - tm * 132;  // n-fast: consecutive blocks share A panel
  const int m0 = tm << 7, n0 = tn << 7;
  const int tid = threadIdx.x;
  const int lane = tid & 63;
  const int w = tid >> 6;
  const int wm = w >> 1, wn = w & 1;
  const int fr = lane & 15, fq = lane >> 4;

  f32x4 acc[4][4];
#pragma unroll
  for (int i = 0; i < 4; ++i)
#pragma unroll
    for (int j = 0; j < 4; ++j) acc[i][j] = (f32x4){0.f, 0.f, 0.f, 0.f};

  const int srow = (w << 5) + (lane >> 2);   // staging row within tile (per issue +16)
  const int scol = (lane & 3) << 3;          // staging col (8 bf16 = 16B)
  const unsigned short* gA = A + (size_t)(m0 + srow) * 1024 + scol;
  const unsigned short* gB = W + (size_t)(n0 + srow) * 1024 + scol;

  for (int k0 = 0; k0 < 1024; k0 += 32) {
#pragma unroll
    for (int i = 0; i < 2; ++i) {
      gload_lds16(gA + (size_t)(i * 16) * 1024 + k0, &As[(w << 10) + (i << 9)]);
      gload_lds16(gB + (size_t)(i * 16) * 1024 + k0, &Bs[(w << 10) + (i << 9)]);
    }
    __syncthreads();
    bf16x8 af[4], bfr[4];
#pragma unroll
    for (int mi = 0; mi < 4; ++mi)
      af[mi] = *(const bf16x8*)&As[((wm << 6) + (mi << 4) + fr) * 32 + (fq << 3)];
#pragma unroll
    for (int ni = 0; ni < 4; ++ni)
      bfr[ni] = *(const bf16x8*)&Bs[((wn << 6) + (ni << 4) + fr) * 32 + (fq << 3)];
#pragma unroll
    for (int mi = 0; mi < 4; ++mi)
#pragma unroll
      for (int ni = 0; ni < 4; ++ni)
        acc[mi][ni] = __builtin_amdgcn_mfma_f32_16x16x32_bf16(af[mi], bfr[ni], acc[mi][ni], 0, 0, 0);
    __syncthreads();
  }

#pragma unroll
  for (int mi = 0; mi < 4; ++mi)
#pragma unroll
    for (int ni = 0; ni < 4; ++ni)
#pragma unroll
      for (int r = 0; r < 4; ++r) {
        int row = m0 + (wm << 6) + (mi << 4) + (fq << 2) + r;
        int col = n0 + (wn << 6) + (ni << 4) + fr;
        C[(size_t)row * 16896 + col] = f2bf(acc[mi][ni][r]);
      }
}

// ---- epilogue: per n (one wave): U from triu params, S=U U^T via MFMA,
//      col-norm max, y = alpha/(max+eps) * S x, out = x - y ----
__global__ __launch_bounds__(256) void k_epi(const unsigned short* __restrict__ P,
                                             const float* __restrict__ X,
                                             const float* __restrict__ alpha,
                                             float* __restrict__ out) {
  __shared__ __align__(16) unsigned short Ulds[4][1024];  // [wave][32*32] bf16
  __shared__ float Xlds[4][32];
  const int w = threadIdx.x >> 6, lane = threadIdx.x & 63;
  const int n = (blockIdx.x << 2) + w;
  const int bt = n >> 5, c = n & 31;
  unsigned short* U = Ulds[w];

  // zero U (full 32x32)
#pragma unroll
  for (int t = 0; t < 16; ++t) U[lane + (t << 6)] = 0;
  // stage x slice
  if (lane < 32) Xlds[w][lane] = X[(size_t)bt * 1024 + (c << 5) + lane];
  // scatter 528 params into upper triangle (row-major triu order)
  const unsigned short* p = P + (size_t)bt * 16896 + c * 528;
  for (int e = 0; e < 9; ++e) {
    int idx = lane + (e << 6);
    if (idx < 528) {
      unsigned short v = p[idx];
      int i = 0, rem = idx;
      while (rem >= 32 - i) { rem -= 32 - i; ++i; }
      U[(i << 5) + i + rem] = v;  // U[i][i+rem]
    }
  }
  __syncthreads();

  const int fr = lane & 15, fq = lane >> 4;
  // both MFMA operands are U in identical K-contiguous layout (S = U U^T)
  bf16x8 f0 = *(const bf16x8*)&U[fr * 32 + (fq << 3)];         // rows/cols 0..15
  bf16x8 f1 = *(const bf16x8*)&U[(16 + fr) * 32 + (fq << 3)];  // rows/cols 16..31
  f32x4 z = {0.f, 0.f, 0.f, 0.f};
  f32x4 s00 = __builtin_amdgcn_mfma_f32_16x16x32_bf16(f0, f0, z, 0, 0, 0);
  f32x4 s01 = __builtin_amdgcn_mfma_f32_16x16x32_bf16(f0, f1, z, 0, 0, 0);
  f32x4 s10 = __builtin_amdgcn_mfma_f32_16x16x32_bf16(f1, f0, z, 0, 0, 0);
  f32x4 s11 = __builtin_amdgcn_mfma_f32_16x16x32_bf16(f1, f1, z, 0, 0, 0);
  // lane holds S[mi*16 + fq*4 + r][ni*16 + fr]

  // column sum-of-squares: p0 -> col fr, p1 -> col 16+fr
  float p0 = 0.f, p1 = 0.f;
#pragma unroll
  for (int r = 0; r < 4; ++r) {
    p0 += s00[r] * s00[r] + s10[r] * s10[r];
    p1 += s01[r] * s01[r] + s11[r] * s11[r];
  }
  p0 += __shfl_xor(p0, 16); p0 += __shfl_xor(p0, 32);
  p1 += __shfl_xor(p1, 16); p1 += __shfl_xor(p1, 32);
  float m = fmaxf(sqrtf(p0), sqrtf(p1));
#pragma unroll
  for (int off = 1; off < 16; off <<= 1) m = fmaxf(m, __shfl_xor(m, off));
  const float scale = alpha[n] / (m + EPS);

  // y = S x (row partials, reduce over fr lanes)
  const float* xl = Xlds[w];
  const float x0 = xl[fr], x1 = xl[16 + fr];
  float y[8];
#pragma unroll
  for (int r = 0; r < 4; ++r) {
    y[r] = s00[r] * x0 + s01[r] * x1;      // row = fq*4 + r
    y[4 + r] = s10[r] * x0 + s11[r] * x1;  // row = 16 + fq*4 + r
  }
#pragma unroll
  for (int off = 1; off < 16; off <<= 1) {
#pragma unroll
    for (int t = 0; t < 8; ++t) y[t] += __shfl_xor(y[t], off);
  }
  if (fr == 0) {
#pragma unroll
    for (int t = 0; t < 8; ++t) {
      int row = ((t >> 2) << 4) + (fq << 2) + (t & 3);
      out[(size_t)bt * 1024 + (c << 5) + row] = xl[row] - scale * y[t];
    }
  }
}

extern "C" void kernel_launch(void* const* d_in, const int* in_sizes, int n_in,
                              void* d_out, int out_size, void* d_ws, size_t ws_size,
                              hipStream_t stream) {
  const float* param = (const float*)d_in[0];   // [2,2048,1024]
  const float* input = (const float*)d_in[1];   // [2,2048,1024]
  const float* W_uv  = (const float*)d_in[2];   // [16896,1024]
  const float* W_al  = (const float*)d_in[3];   // [32,1024]
  const float* b_al  = (const float*)d_in[4];   // [32]
  float* out = (float*)d_out;

  char* ws = (char*)d_ws;
  unsigned short* Ab    = (unsigned short*)(ws);                      //  8,388,608 B
  unsigned short* Wb    = (unsigned short*)(ws + 8388608);            // 34,603,008 B
  float*          alpha = (float*)(ws + 42991616);                    //    524,288 B
  unsigned short* Pp    = (unsigned short*)(ws + 43515904);           // 138,412,032 B  (total 181,927,936)

  k_convert<<<2048, 256, 0, stream>>>(param, Ab, (4096 * 1024) / 4);
  k_convert<<<4096, 256, 0, stream>>>(W_uv, Wb, (16896 * 1024) / 4);
  k_alpha<<<4096, 256, 0, stream>>>(param, W_al, b_al, alpha);
  k_gemm<<<32 * 132, 256, 0, stream>>>(Ab, Wb, Pp);
  k_epi<<<131072 / 4, 256, 0, stream>>>(Pp, input, alpha, out);
}

// Round 2
// 377.060 us; speedup vs baseline: 1.0914x; 1.0914x over previous
//
#include <hip/hip_runtime.h>
#include <hip/hip_bf16.h>
#include <stdint.h>

typedef float f32x4 __attribute__((ext_vector_type(4)));
typedef __bf16 bf16x8 __attribute__((ext_vector_type(8)));

#define EPS 1e-5f

// ---- helpers ----
static __device__ __forceinline__ unsigned short f2bf(float f) {
  unsigned int u = __float_as_uint(f);
  unsigned int r = (u + 0x7fffu + ((u >> 16) & 1u)) >> 16;
  return (unsigned short)r;
}

static __device__ __forceinline__ void gload_lds16(const unsigned short* g, unsigned short* s) {
  __builtin_amdgcn_global_load_lds((const __attribute__((address_space(1))) unsigned int*)g,
                                   (__attribute__((address_space(3))) unsigned int*)s,
                                   16, 0, 0);
}

// ---- fp32 -> bf16 convert (vectorized) ----
__global__ void k_convert(const float* __restrict__ src, unsigned short* __restrict__ dst, int n4) {
  int idx = blockIdx.x * blockDim.x + threadIdx.x;
  int stride = gridDim.x * blockDim.x;
  for (int i = idx; i < n4; i += stride) {
    f32x4 v = ((const f32x4*)src)[i];
    ushort4 o;
    o.x = f2bf(v.x); o.y = f2bf(v.y); o.z = f2bf(v.z); o.w = f2bf(v.w);
    ((ushort4*)dst)[i] = o;
  }
}

// ---- alpha = sigmoid(A @ W_alpha^T + b), fused with param->bf16 convert ----
__global__ __launch_bounds__(256) void k_alpha(const float* __restrict__ A,
                                               const float* __restrict__ Wa,
                                               const float* __restrict__ ba,
                                               float* __restrict__ alpha,
                                               unsigned short* __restrict__ Ab) {
  __shared__ __align__(16) float arow[1024];
  const int bt = blockIdx.x, tid = threadIdx.x;
  f32x4 v = ((const f32x4*)(A + (size_t)bt * 1024))[tid];
  ((f32x4*)arow)[tid] = v;
  ushort4 o;
  o.x = f2bf(v.x); o.y = f2bf(v.y); o.z = f2bf(v.z); o.w = f2bf(v.w);
  ((ushort4*)(Ab + (size_t)bt * 1024))[tid] = o;
  __syncthreads();
  const int c = tid >> 3, h = tid & 7;
  const float* wr = Wa + (size_t)c * 1024 + h * 128;
  const float* ar = arow + h * 128;
  float s = 0.f;
#pragma unroll 8
  for (int j = 0; j < 128; j += 4) {
    f32x4 wv = *(const f32x4*)(wr + j);
    s += wv.x * ar[j] + wv.y * ar[j + 1] + wv.z * ar[j + 2] + wv.w * ar[j + 3];
  }
  s += __shfl_down(s, 4);
  s += __shfl_down(s, 2);
  s += __shfl_down(s, 1);
  if (h == 0) {
    float z = s + ba[c];
    alpha[(size_t)bt * 32 + c] = 1.f / (1.f + __expf(-z));
  }
}

// ---- main GEMM: C[4096,16896] = A[4096,1024] @ W^T, bf16 in, bf16 out ----
// m97 structure: 128x128 tile, BK=32, 4 waves of 64x64, 16x16x32 MFMA.
__global__ __launch_bounds__(256) void k_gemm(const unsigned short* __restrict__ A,
                                              const unsigned short* __restrict__ W,
                                              unsigned short* __restrict__ C) {
  __shared__ __align__(16) unsigned short As[4096];  // [128][32]
  __shared__ __align__(16) unsigned short Bs[4096];  // [128][32]
  // XCD-aware bijective swizzle: grid 4224 = 8 * 528
  const int bid0 = blockIdx.x;
  const int bid = (bid0 & 7) * 528 + (bid0 >> 3);
  const int tm = bid / 132, tn = bid - tm * 132;  // n-fast within chunk
  const int m0 = tm << 7, n0 = tn << 7;
  const int tid = threadIdx.x;
  const int lane = tid & 63;
  const int w = tid >> 6;
  const int wm = w >> 1, wn = w & 1;
  const int fr = lane & 15, fq = lane >> 4;

  f32x4 acc[4][4];
#pragma unroll
  for (int i = 0; i < 4; ++i)
#pragma unroll
    for (int j = 0; j < 4; ++j) acc[i][j] = (f32x4){0.f, 0.f, 0.f, 0.f};

  const int srow = (w << 5) + (lane >> 2);   // staging row within tile (per issue +16)
  const int scol = (lane & 3) << 3;          // staging col (8 bf16 = 16B)
  const unsigned short* gA = A + (size_t)(m0 + srow) * 1024 + scol;
  const unsigned short* gB = W + (size_t)(n0 + srow) * 1024 + scol;

  for (int k0 = 0; k0 < 1024; k0 += 32) {
#pragma unroll
    for (int i = 0; i < 2; ++i) {
      gload_lds16(gA + (size_t)(i * 16) * 1024 + k0, &As[(w << 10) + (i << 9)]);
      gload_lds16(gB + (size_t)(i * 16) * 1024 + k0, &Bs[(w << 10) + (i << 9)]);
    }
    __syncthreads();
    bf16x8 af[4], bfr[4];
#pragma unroll
    for (int mi = 0; mi < 4; ++mi)
      af[mi] = *(const bf16x8*)&As[((wm << 6) + (mi << 4) + fr) * 32 + (fq << 3)];
#pragma unroll
    for (int ni = 0; ni < 4; ++ni)
      bfr[ni] = *(const bf16x8*)&Bs[((wn << 6) + (ni << 4) + fr) * 32 + (fq << 3)];
#pragma unroll
    for (int mi = 0; mi < 4; ++mi)
#pragma unroll
      for (int ni = 0; ni < 4; ++ni)
        acc[mi][ni] = __builtin_amdgcn_mfma_f32_16x16x32_bf16(af[mi], bfr[ni], acc[mi][ni], 0, 0, 0);
    __syncthreads();
  }

#pragma unroll
  for (int mi = 0; mi < 4; ++mi)
#pragma unroll
    for (int ni = 0; ni < 4; ++ni)
#pragma unroll
      for (int r = 0; r < 4; ++r) {
        int row = m0 + (wm << 6) + (mi << 4) + (fq << 2) + r;
        int col = n0 + (wn << 6) + (ni << 4) + fr;
        C[(size_t)row * 16896 + col] = f2bf(acc[mi][ni][r]);
      }
}

// ---- epilogue: per n (one wave): U from triu params, S=U U^T via MFMA,
//      col-norm max, y = alpha/(max+eps) * S x, out = x - y ----
__global__ __launch_bounds__(256) void k_epi(const unsigned short* __restrict__ P,
                                             const float* __restrict__ X,
                                             const float* __restrict__ alpha,
                                             float* __restrict__ out) {
  __shared__ __align__(16) unsigned short Ulds[4][1024];  // [wave][32*32] bf16
  __shared__ float Xlds[4][32];
  __shared__ float Ylds[4][32];
  const int w = threadIdx.x >> 6, lane = threadIdx.x & 63;
  const int n = (blockIdx.x << 2) + w;
  const int bt = n >> 5, c = n & 31;
  unsigned short* U = Ulds[w];

  // zero U (full 32x32) with 8B stores: 256 ushort4 = 64 lanes x 4
#pragma unroll
  for (int t = 0; t < 4; ++t) ((ushort4*)U)[lane + (t << 6)] = make_ushort4(0, 0, 0, 0);
  // stage x slice
  if (lane < 32) Xlds[w][lane] = X[(size_t)bt * 1024 + (c << 5) + lane];
  // scatter 528 params into upper triangle (row-major triu order)
  // closed-form row decode: 8*o_i = 4225 - (65-2i)^2  =>  i = floor((65-sqrt(4225-8idx))/2)
  const unsigned short* p = P + (size_t)bt * 16896 + c * 528;
#pragma unroll
  for (int e = 0; e < 9; ++e) {
    int idx = lane + (e << 6);
    if (idx < 528) {
      unsigned short v = p[idx];
      float fi = (65.0f - sqrtf((float)(4225 - 8 * idx))) * 0.5f;
      int i = (int)fi;
      int oi = (i * (65 - i)) >> 1;
      if (idx < oi) { --i; oi = (i * (65 - i)) >> 1; }
      else { int oi1 = ((i + 1) * (64 - i)) >> 1; if (idx >= oi1) { oi = oi1; ++i; } }
      U[(i << 5) + i + (idx - oi)] = v;  // U[i][j], j = i + (idx - o_i)
    }
  }
  __syncthreads();

  const int fr = lane & 15, fq = lane >> 4;
  // both MFMA operands are U in identical K-contiguous layout (S = U U^T)
  bf16x8 f0 = *(const bf16x8*)&U[fr * 32 + (fq << 3)];         // rows/cols 0..15
  bf16x8 f1 = *(const bf16x8*)&U[(16 + fr) * 32 + (fq << 3)];  // rows/cols 16..31
  f32x4 z = {0.f, 0.f, 0.f, 0.f};
  f32x4 s00 = __builtin_amdgcn_mfma_f32_16x16x32_bf16(f0, f0, z, 0, 0, 0);
  f32x4 s01 = __builtin_amdgcn_mfma_f32_16x16x32_bf16(f0, f1, z, 0, 0, 0);
  f32x4 s10 = __builtin_amdgcn_mfma_f32_16x16x32_bf16(f1, f0, z, 0, 0, 0);
  f32x4 s11 = __builtin_amdgcn_mfma_f32_16x16x32_bf16(f1, f1, z, 0, 0, 0);
  // lane holds S[mi*16 + fq*4 + r][ni*16 + fr]

  // column sum-of-squares: p0 -> col fr, p1 -> col 16+fr
  float p0 = 0.f, p1 = 0.f;
#pragma unroll
  for (int r = 0; r < 4; ++r) {
    p0 += s00[r] * s00[r] + s10[r] * s10[r];
    p1 += s01[r] * s01[r] + s11[r] * s11[r];
  }
  p0 += __shfl_xor(p0, 16); p0 += __shfl_xor(p0, 32);
  p1 += __shfl_xor(p1, 16); p1 += __shfl_xor(p1, 32);
  float m = fmaxf(sqrtf(p0), sqrtf(p1));
#pragma unroll
  for (int off = 1; off < 16; off <<= 1) m = fmaxf(m, __shfl_xor(m, off));
  const float scale = alpha[n] / (m + EPS);

  // y = S x (row partials, reduce over fr lanes)
  const float* xl = Xlds[w];
  const float x0 = xl[fr], x1 = xl[16 + fr];
  float y[8];
#pragma unroll
  for (int r = 0; r < 4; ++r) {
    y[r] = s00[r] * x0 + s01[r] * x1;      // row = fq*4 + r
    y[4 + r] = s10[r] * x0 + s11[r] * x1;  // row = 16 + fq*4 + r
  }
#pragma unroll
  for (int off = 1; off < 16; off <<= 1) {
#pragma unroll
    for (int t = 0; t < 8; ++t) y[t] += __shfl_xor(y[t], off);
  }
  if (fr == 0) {
#pragma unroll
    for (int t = 0; t < 8; ++t) {
      int row = ((t >> 2) << 4) + (fq << 2) + (t & 3);
      Ylds[w][row] = y[t];
    }
  }
  __syncthreads();
  if (lane < 32) {
    float xv = Xlds[w][lane];
    out[(size_t)bt * 1024 + (c << 5) + lane] = xv - scale * Ylds[w][lane];
  }
}

extern "C" void kernel_launch(void* const* d_in, const int* in_sizes, int n_in,
                              void* d_out, int out_size, void* d_ws, size_t ws_size,
                              hipStream_t stream) {
  const float* param = (const float*)d_in[0];   // [2,2048,1024]
  const float* input = (const float*)d_in[1];   // [2,2048,1024]
  const float* W_uv  = (const float*)d_in[2];   // [16896,1024]
  const float* W_al  = (const float*)d_in[3];   // [32,1024]
  const float* b_al  = (const float*)d_in[4];   // [32]
  float* out = (float*)d_out;

  char* ws = (char*)d_ws;
  unsigned short* Ab    = (unsigned short*)(ws);                      //  8,388,608 B
  unsigned short* Wb    = (unsigned short*)(ws + 8388608);            // 34,603,008 B
  float*          alpha = (float*)(ws + 42991616);                    //    524,288 B
  unsigned short* Pp    = (unsigned short*)(ws + 43515904);           // 138,412,032 B  (total 181,927,936)

  k_convert<<<4096, 256, 0, stream>>>(W_uv, Wb, (16896 * 1024) / 4);
  k_alpha<<<4096, 256, 0, stream>>>(param, W_al, b_al, alpha, Ab);
  k_gemm<<<32 * 132, 256, 0, stream>>>(Ab, Wb, Pp);
  k_epi<<<131072 / 4, 256, 0, stream>>>(Pp, input, alpha, out);
}

// Round 3
// 310.647 us; speedup vs baseline: 1.3248x; 1.2138x over previous
//
#include <hip/hip_runtime.h>
#include <hip/hip_bf16.h>
#include <stdint.h>

typedef float f32x4 __attribute__((ext_vector_type(4)));
typedef float f32x16 __attribute__((ext_vector_type(16)));
typedef __bf16 bf16x8 __attribute__((ext_vector_type(8)));

#define EPS 1e-5f

// ---- helpers ----
static __device__ __forceinline__ unsigned short f2bf(float f) {
  unsigned int u = __float_as_uint(f);
  unsigned int r = (u + 0x7fffu + ((u >> 16) & 1u)) >> 16;
  return (unsigned short)r;
}

static __device__ __forceinline__ void gload_lds16(const unsigned short* g, unsigned short* s) {
  __builtin_amdgcn_global_load_lds((const __attribute__((address_space(1))) unsigned int*)g,
                                   (__attribute__((address_space(3))) unsigned int*)s,
                                   16, 0, 0);
}

// ---- fp32 -> bf16 convert (vectorized) ----
__global__ void k_convert(const float* __restrict__ src, unsigned short* __restrict__ dst, int n4) {
  int idx = blockIdx.x * blockDim.x + threadIdx.x;
  int stride = gridDim.x * blockDim.x;
  for (int i = idx; i < n4; i += stride) {
    f32x4 v = ((const f32x4*)src)[i];
    ushort4 o;
    o.x = f2bf(v.x); o.y = f2bf(v.y); o.z = f2bf(v.z); o.w = f2bf(v.w);
    ((ushort4*)dst)[i] = o;
  }
}

// ---- alpha = sigmoid(A @ W_alpha^T + b), fused with param->bf16 convert ----
__global__ __launch_bounds__(256) void k_alpha(const float* __restrict__ A,
                                               const float* __restrict__ Wa,
                                               const float* __restrict__ ba,
                                               float* __restrict__ alpha,
                                               unsigned short* __restrict__ Ab) {
  __shared__ __align__(16) float arow[1024];
  const int bt = blockIdx.x, tid = threadIdx.x;
  f32x4 v = ((const f32x4*)(A + (size_t)bt * 1024))[tid];
  ((f32x4*)arow)[tid] = v;
  ushort4 o;
  o.x = f2bf(v.x); o.y = f2bf(v.y); o.z = f2bf(v.z); o.w = f2bf(v.w);
  ((ushort4*)(Ab + (size_t)bt * 1024))[tid] = o;
  __syncthreads();
  const int c = tid >> 3, h = tid & 7;
  const float* wr = Wa + (size_t)c * 1024 + h * 128;
  const float* ar = arow + h * 128;
  float s = 0.f;
#pragma unroll 8
  for (int j = 0; j < 128; j += 4) {
    f32x4 wv = *(const f32x4*)(wr + j);
    s += wv.x * ar[j] + wv.y * ar[j + 1] + wv.z * ar[j + 2] + wv.w * ar[j + 3];
  }
  s += __shfl_down(s, 4);
  s += __shfl_down(s, 2);
  s += __shfl_down(s, 1);
  if (h == 0) {
    float z = s + ba[c];
    alpha[(size_t)bt * 32 + c] = 1.f / (1.f + __expf(-z));
  }
}

// ---- main GEMM: C[4096,16896] = A[4096,1024] @ W^T, bf16 in, bf16 out ----
// m97 structure: 128x128 tile, BK=32, 4 waves of 64x64, 16x16x32 MFMA.
// No XCD swizzle: measured +14us / +2.3x FETCH_SIZE with chunked swizzle (R2).
__global__ __launch_bounds__(256) void k_gemm(const unsigned short* __restrict__ A,
                                              const unsigned short* __restrict__ W,
                                              unsigned short* __restrict__ C) {
  __shared__ __align__(16) unsigned short As[4096];  // [128][32]
  __shared__ __align__(16) unsigned short Bs[4096];  // [128][32]
  const int bid = blockIdx.x;
  const int tm = bid / 132, tn = bid - tm * 132;  // n-fast: consecutive blocks share A panel
  const int m0 = tm << 7, n0 = tn << 7;
  const int tid = threadIdx.x;
  const int lane = tid & 63;
  const int w = tid >> 6;
  const int wm = w >> 1, wn = w & 1;
  const int fr = lane & 15, fq = lane >> 4;

  f32x4 acc[4][4];
#pragma unroll
  for (int i = 0; i < 4; ++i)
#pragma unroll
    for (int j = 0; j < 4; ++j) acc[i][j] = (f32x4){0.f, 0.f, 0.f, 0.f};

  const int srow = (w << 5) + (lane >> 2);   // staging row within tile (per issue +16)
  const int scol = (lane & 3) << 3;          // staging col (8 bf16 = 16B)
  const unsigned short* gA = A + (size_t)(m0 + srow) * 1024 + scol;
  const unsigned short* gB = W + (size_t)(n0 + srow) * 1024 + scol;

  for (int k0 = 0; k0 < 1024; k0 += 32) {
#pragma unroll
    for (int i = 0; i < 2; ++i) {
      gload_lds16(gA + (size_t)(i * 16) * 1024 + k0, &As[(w << 10) + (i << 9)]);
      gload_lds16(gB + (size_t)(i * 16) * 1024 + k0, &Bs[(w << 10) + (i << 9)]);
    }
    __syncthreads();
    bf16x8 af[4], bfr[4];
#pragma unroll
    for (int mi = 0; mi < 4; ++mi)
      af[mi] = *(const bf16x8*)&As[((wm << 6) + (mi << 4) + fr) * 32 + (fq << 3)];
#pragma unroll
    for (int ni = 0; ni < 4; ++ni)
      bfr[ni] = *(const bf16x8*)&Bs[((wn << 6) + (ni << 4) + fr) * 32 + (fq << 3)];
#pragma unroll
    for (int mi = 0; mi < 4; ++mi)
#pragma unroll
      for (int ni = 0; ni < 4; ++ni)
        acc[mi][ni] = __builtin_amdgcn_mfma_f32_16x16x32_bf16(af[mi], bfr[ni], acc[mi][ni], 0, 0, 0);
    __syncthreads();
  }

#pragma unroll
  for (int mi = 0; mi < 4; ++mi)
#pragma unroll
    for (int ni = 0; ni < 4; ++ni)
#pragma unroll
      for (int r = 0; r < 4; ++r) {
        int row = m0 + (wm << 6) + (mi << 4) + (fq << 2) + r;
        int col = n0 + (wn << 6) + (ni << 4) + fr;
        C[(size_t)row * 16896 + col] = f2bf(acc[mi][ni][r]);
      }
}

// ---- epilogue: per n (one wave): U from triu params, S = U U^T via one
//      32x32x16 MFMA pair; reductions are lane-local + 1 shfl thanks to the
//      32x32 C/D layout (col=lane&31, row=(r&3)+8*(r>>2)+4*(lane>>5)).
//      y_j = sum_i x_i S_ij == (Sx)_j by symmetry -> row-reduce in registers.
__global__ __launch_bounds__(256) void k_epi(const unsigned short* __restrict__ P,
                                             const float* __restrict__ X,
                                             const float* __restrict__ alpha,
                                             float* __restrict__ out) {
  __shared__ __align__(16) unsigned short U[4][1280];  // [wave][32 rows x 40 stride]
  __shared__ __align__(16) float Xl[4][32];
  __shared__ unsigned short tab[528];
  const int tid = threadIdx.x;
  // per-block triu decode table (amortized over 4 n's)
  for (int e = tid; e < 528; e += 256) {
    float fi = (65.0f - sqrtf((float)(4225 - 8 * e))) * 0.5f;
    int i = (int)fi;
    int oi = (i * (65 - i)) >> 1;
    if (e < oi) { --i; oi = (i * (65 - i)) >> 1; }
    else { int oi1 = ((i + 1) * (64 - i)) >> 1; if (e >= oi1) { oi = oi1; ++i; } }
    tab[e] = (unsigned short)(i * 40 + i + (e - oi));  // U[i][j], stride 40
  }
  const int w = tid >> 6, lane = tid & 63;
  const int n = (blockIdx.x << 2) + w;
  const int bt = n >> 5, c = n & 31;
  unsigned short* Uw = U[w];
  // zero U (1280 shorts = 320 ushort4)
#pragma unroll
  for (int t = 0; t < 5; ++t) ((ushort4*)Uw)[lane + (t << 6)] = make_ushort4(0, 0, 0, 0);
  if (lane < 32) Xl[w][lane] = X[(size_t)bt * 1024 + (c << 5) + lane];
  __syncthreads();  // table ready; zero/X ordered before scatter/reads

  const unsigned short* p = P + (size_t)bt * 16896 + c * 528;
#pragma unroll
  for (int e = 0; e < 9; ++e) {
    int idx = lane + (e << 6);
    if (idx < 528) Uw[tab[idx]] = p[idx];  // same-wave DS ops are in-order
  }

  const int col = lane & 31, hi = lane >> 5;
  // A-frag == B-frag: row/col = lane&31, k = hi*8 + e (analog of verified 16x16 layout)
  bf16x8 fa0 = *(const bf16x8*)&Uw[col * 40 + (hi << 3)];       // k 0..15
  bf16x8 fa1 = *(const bf16x8*)&Uw[col * 40 + 16 + (hi << 3)];  // k 16..31
  f32x16 S = {0.f, 0.f, 0.f, 0.f, 0.f, 0.f, 0.f, 0.f, 0.f, 0.f, 0.f, 0.f, 0.f, 0.f, 0.f, 0.f};
  S = __builtin_amdgcn_mfma_f32_32x32x16_bf16(fa0, fa0, S, 0, 0, 0);
  S = __builtin_amdgcn_mfma_f32_32x32x16_bf16(fa1, fa1, S, 0, 0, 0);
  // lane holds S[row=(r&3)+8*(r>>2)+4*hi][col] for r in 0..15

  // column sum of squares (16 rows here + 16 in partner lane)
  float css = 0.f;
#pragma unroll
  for (int r = 0; r < 16; ++r) css += S[r] * S[r];
  css += __shfl_xor(css, 32);
  float m = css;
#pragma unroll
  for (int off = 1; off < 32; off <<= 1) m = fmaxf(m, __shfl_xor(m, off));
  m = sqrtf(m);  // max of sqrt == sqrt of max
  const float scale = alpha[n] / (m + EPS);

  // y_j = sum_i x_i S_ij : in-register over this lane's 16 rows + 1 shfl
  const float* xw = Xl[w];
  f32x4 x0 = *(const f32x4*)&xw[(hi << 2)];
  f32x4 x1 = *(const f32x4*)&xw[8 + (hi << 2)];
  f32x4 x2 = *(const f32x4*)&xw[16 + (hi << 2)];
  f32x4 x3 = *(const f32x4*)&xw[24 + (hi << 2)];
  float y = 0.f;
#pragma unroll
  for (int r = 0; r < 4; ++r) y += x0[r] * S[r];
#pragma unroll
  for (int r = 0; r < 4; ++r) y += x1[r] * S[4 + r];
#pragma unroll
  for (int r = 0; r < 4; ++r) y += x2[r] * S[8 + r];
#pragma unroll
  for (int r = 0; r < 4; ++r) y += x3[r] * S[12 + r];
  y += __shfl_xor(y, 32);

  if (hi == 0) {
    out[(size_t)bt * 1024 + (c << 5) + col] = xw[col] - scale * y;
  }
}

extern "C" void kernel_launch(void* const* d_in, const int* in_sizes, int n_in,
                              void* d_out, int out_size, void* d_ws, size_t ws_size,
                              hipStream_t stream) {
  const float* param = (const float*)d_in[0];   // [2,2048,1024]
  const float* input = (const float*)d_in[1];   // [2,2048,1024]
  const float* W_uv  = (const float*)d_in[2];   // [16896,1024]
  const float* W_al  = (const float*)d_in[3];   // [32,1024]
  const float* b_al  = (const float*)d_in[4];   // [32]
  float* out = (float*)d_out;

  char* ws = (char*)d_ws;
  unsigned short* Ab    = (unsigned short*)(ws);                      //  8,388,608 B
  unsigned short* Wb    = (unsigned short*)(ws + 8388608);            // 34,603,008 B
  float*          alpha = (float*)(ws + 42991616);                    //    524,288 B
  unsigned short* Pp    = (unsigned short*)(ws + 43515904);           // 138,412,032 B  (total 181,927,936)

  k_convert<<<4096, 256, 0, stream>>>(W_uv, Wb, (16896 * 1024) / 4);
  k_alpha<<<4096, 256, 0, stream>>>(param, W_al, b_al, alpha, Ab);
  k_gemm<<<32 * 132, 256, 0, stream>>>(Ab, Wb, Pp);
  k_epi<<<131072 / 4, 256, 0, stream>>>(Pp, input, alpha, out);
}